// Round 1
// baseline (477.394 us; speedup 1.0000x reference)
//
#include <hip/hip_runtime.h>

#define NF 64
#define ALPHA 0.2f

// Kernel A: Wh = h @ W.T + Wb ; s_src[n] = Wh[n]@a[:64] ; s_dst[n] = Wh[n]@a[64:]
// One wave (64 lanes) per node row. W transposed into LDS with stride-65 padding.
__global__ __launch_bounds__(256) void wh_kernel(
    const float* __restrict__ h, const float* __restrict__ W,
    const float* __restrict__ Wb, const float* __restrict__ a,
    float* __restrict__ Wh, float* __restrict__ s_src, float* __restrict__ s_dst,
    int N)
{
    __shared__ float Wt[64 * 65];   // Wt[j*65+i] = W[i*64+j]
    __shared__ float as_[64], ad_[64];
    int tid = threadIdx.x;
    for (int x = tid; x < 4096; x += 256) {
        int i = x >> 6, j = x & 63;
        Wt[j * 65 + i] = W[x];
    }
    if (tid < 64) { as_[tid] = a[tid]; ad_[tid] = a[64 + tid]; }
    __syncthreads();

    int row  = (blockIdx.x * 256 + tid) >> 6;
    int lane = tid & 63;
    if (row >= N) return;

    float hv = h[(size_t)row * 64 + lane];
    float acc = 0.f;
    #pragma unroll
    for (int j = 0; j < 64; ++j) {
        float hj = __shfl(hv, j, 64);
        acc += hj * Wt[j * 65 + lane];
    }
    acc += Wb[lane];
    Wh[(size_t)row * 64 + lane] = acc;

    float p1 = acc * as_[lane];
    float p2 = acc * ad_[lane];
    #pragma unroll
    for (int off = 32; off >= 1; off >>= 1) {
        p1 += __shfl_down(p1, off, 64);
        p2 += __shfl_down(p2, off, 64);
    }
    if (lane == 0) { s_src[row] = p1; s_dst[row] = p2; }
}

// Kernel B: per-edge logit -> exp -> denom accumulation.
// Softmax ratio is invariant to the m[dst] shift; |e| <~ 6 so exp is safe.
__global__ __launch_bounds__(256) void edge_kernel(
    const int* __restrict__ src, const int* __restrict__ dst,
    const float* __restrict__ s_src, const float* __restrict__ s_dst,
    const float* __restrict__ ab,
    float* __restrict__ ex, float* __restrict__ denom, int E)
{
    int k = blockIdx.x * 256 + threadIdx.x;
    if (k >= E) return;
    float e = s_src[src[k]] + s_dst[dst[k]] + ab[0];
    e = e > 0.f ? e : ALPHA * e;
    float v = expf(e);
    ex[k] = v;
    atomicAdd(&denom[dst[k]], v);
}

// Kernel C: one wave per edge; lane f scatters attn * Wh[src][f] into out[dst][f].
__global__ __launch_bounds__(256) void aggregate_kernel(
    const int* __restrict__ src, const int* __restrict__ dst,
    const float* __restrict__ Wh, const float* __restrict__ ex,
    const float* __restrict__ denom, float* __restrict__ out, int E)
{
    int w    = (blockIdx.x * 256 + threadIdx.x) >> 6;
    int lane = threadIdx.x & 63;
    if (w >= E) return;
    int d = dst[w], s = src[w];
    float dn = denom[d];
    float attn = ex[w] / (dn > 0.f ? dn : 1.f);
    atomicAdd(&out[(size_t)d * 64 + lane], attn * Wh[(size_t)s * 64 + lane]);
}

extern "C" void kernel_launch(void* const* d_in, const int* in_sizes, int n_in,
                              void* d_out, int out_size, void* d_ws, size_t ws_size,
                              hipStream_t stream) {
    const float* h   = (const float*)d_in[0];
    const float* W   = (const float*)d_in[1];
    const float* Wb  = (const float*)d_in[2];
    const float* a   = (const float*)d_in[3];
    const float* ab  = (const float*)d_in[4];
    const int*   src = (const int*)d_in[5];
    const int*   dst = (const int*)d_in[6];

    int N = in_sizes[0] / NF;
    int E = in_sizes[5];
    float* out = (float*)d_out;

    float* Wh    = (float*)d_ws;
    float* s_src = Wh + (size_t)N * NF;
    float* s_dst = s_src + N;
    float* ex    = s_dst + N;
    float* denom = ex + E;

    hipMemsetAsync(d_out, 0, (size_t)out_size * sizeof(float), stream);
    hipMemsetAsync(denom, 0, (size_t)N * sizeof(float), stream);

    wh_kernel<<<(N + 3) / 4, 256, 0, stream>>>(h, W, Wb, a, Wh, s_src, s_dst, N);
    edge_kernel<<<(E + 255) / 256, 256, 0, stream>>>(src, dst, s_src, s_dst, ab, ex, denom, E);

    long long totalThreads = (long long)E * 64;
    int blocksC = (int)((totalThreads + 255) / 256);
    aggregate_kernel<<<blocksC, 256, 0, stream>>>(src, dst, Wh, ex, denom, out, E);
}

// Round 2
// 316.871 us; speedup vs baseline: 1.5066x; 1.5066x over previous
//
#include <hip/hip_runtime.h>

#define NF 64
#define ALPHA 0.2f

// ---------------- Kernel 1: Wh = h @ W.T + Wb, s_src = Wh@a[:64], s_dst = Wh@a[64:]
// Block = 256 threads, 64 rows/block, 4x4 register tile per thread.
// out[r][j] = sum_i h[r][i] * W[j][i]  (both rows contiguous -> float4 LDS reads)
__global__ __launch_bounds__(256) void wh_kernel(
    const float* __restrict__ h, const float* __restrict__ W,
    const float* __restrict__ Wb, const float* __restrict__ a,
    float* __restrict__ Wh, float* __restrict__ s_src, float* __restrict__ s_dst,
    int N)
{
    __shared__ float hs[64 * 68];       // stride 68: 16B-aligned rows
    __shared__ float Ws[64 * 64];       // quad-swizzled: W[j][4q+i] at Ws[j*64 + ((q+j)&15)*4 + i]
    __shared__ float wbs[64], as_[64], ad_[64];
    int t = threadIdx.x;
    int r0 = blockIdx.x * 64;

    const float4* W4 = (const float4*)W;
    #pragma unroll
    for (int i = 0; i < 4; ++i) {
        int idx = t + 256 * i;          // 0..1023 quads
        int row = idx >> 4, q = idx & 15;
        float4 w = W4[idx];
        *(float4*)&Ws[row * 64 + ((q + row) & 15) * 4] = w;

        float4 v = make_float4(0.f, 0.f, 0.f, 0.f);
        if (r0 + row < N) v = *(const float4*)&h[(size_t)(r0 + row) * 64 + q * 4];
        *(float4*)&hs[row * 68 + q * 4] = v;
    }
    if (t < 64) { wbs[t] = Wb[t]; as_[t] = a[t]; ad_[t] = a[64 + t]; }
    __syncthreads();

    int tr = t >> 4, tc = t & 15;       // rows 4*tr.., cols 4*tc..
    float acc[4][4];
    #pragma unroll
    for (int rr = 0; rr < 4; ++rr)
        #pragma unroll
        for (int cc = 0; cc < 4; ++cc) acc[rr][cc] = 0.f;

    #pragma unroll
    for (int k = 0; k < 16; ++k) {
        float4 hv[4], wv[4];
        #pragma unroll
        for (int rr = 0; rr < 4; ++rr)
            hv[rr] = *(float4*)&hs[(4 * tr + rr) * 68 + 4 * k];
        #pragma unroll
        for (int cc = 0; cc < 4; ++cc) {
            int j = 4 * tc + cc;
            wv[cc] = *(float4*)&Ws[j * 64 + ((k + j) & 15) * 4];
        }
        #pragma unroll
        for (int rr = 0; rr < 4; ++rr)
            #pragma unroll
            for (int cc = 0; cc < 4; ++cc)
                acc[rr][cc] += hv[rr].x * wv[cc].x + hv[rr].y * wv[cc].y
                             + hv[rr].z * wv[cc].z + hv[rr].w * wv[cc].w;
    }

    float p1[4], p2[4];
    #pragma unroll
    for (int rr = 0; rr < 4; ++rr) {
        int row = r0 + 4 * tr + rr;
        float4 o;
        o.x = acc[rr][0] + wbs[4 * tc + 0];
        o.y = acc[rr][1] + wbs[4 * tc + 1];
        o.z = acc[rr][2] + wbs[4 * tc + 2];
        o.w = acc[rr][3] + wbs[4 * tc + 3];
        if (row < N) *(float4*)&Wh[(size_t)row * 64 + 4 * tc] = o;
        p1[rr] = o.x * as_[4 * tc] + o.y * as_[4 * tc + 1] + o.z * as_[4 * tc + 2] + o.w * as_[4 * tc + 3];
        p2[rr] = o.x * ad_[4 * tc] + o.y * ad_[4 * tc + 1] + o.z * ad_[4 * tc + 2] + o.w * ad_[4 * tc + 3];
    }
    #pragma unroll
    for (int off = 8; off >= 1; off >>= 1) {
        #pragma unroll
        for (int rr = 0; rr < 4; ++rr) {
            p1[rr] += __shfl_down(p1[rr], off, 16);
            p2[rr] += __shfl_down(p2[rr], off, 16);
        }
    }
    if (tc == 0) {
        #pragma unroll
        for (int rr = 0; rr < 4; ++rr) {
            int row = r0 + 4 * tr + rr;
            if (row < N) { s_src[row] = p1[rr]; s_dst[row] = p2[rr]; }
        }
    }
}

// ---------------- CSR build ----------------
__global__ __launch_bounds__(256) void hist_kernel(
    const int* __restrict__ dst, int* __restrict__ c, int E)
{
    int k = blockIdx.x * 256 + threadIdx.x;
    if (k < E) atomicAdd(&c[dst[k]], 1);
}

// exclusive scan, 1024 elems/block (256 threads x 4), in place; block totals -> bsum
__global__ __launch_bounds__(256) void scan_a(int* __restrict__ c, int* __restrict__ bsum, int n)
{
    __shared__ int s[256];
    int t = threadIdx.x;
    int base = blockIdx.x * 1024 + t * 4;
    int v0 = 0, v1 = 0, v2 = 0, v3 = 0;
    if (base + 0 < n) v0 = c[base + 0];
    if (base + 1 < n) v1 = c[base + 1];
    if (base + 2 < n) v2 = c[base + 2];
    if (base + 3 < n) v3 = c[base + 3];
    int tsum = v0 + v1 + v2 + v3;
    s[t] = tsum; __syncthreads();
    for (int off = 1; off < 256; off <<= 1) {
        int x = (t >= off) ? s[t - off] : 0;
        __syncthreads();
        s[t] += x;
        __syncthreads();
    }
    int excl = s[t] - tsum;
    if (base + 0 < n) c[base + 0] = excl; excl += v0;
    if (base + 1 < n) c[base + 1] = excl; excl += v1;
    if (base + 2 < n) c[base + 2] = excl; excl += v2;
    if (base + 3 < n) c[base + 3] = excl;
    if (t == 255) bsum[blockIdx.x] = s[255];
}

__global__ __launch_bounds__(256) void scan_b(int* __restrict__ bsum, int nb)
{
    __shared__ int s[256];
    int t = threadIdx.x;
    int v = (t < nb) ? bsum[t] : 0;
    s[t] = v; __syncthreads();
    for (int off = 1; off < 256; off <<= 1) {
        int x = (t >= off) ? s[t - off] : 0;
        __syncthreads();
        s[t] += x;
        __syncthreads();
    }
    if (t < nb) bsum[t] = s[t] - v;
}

__global__ __launch_bounds__(256) void scan_c(int* __restrict__ c, const int* __restrict__ bsum, int n)
{
    int base = blockIdx.x * 1024 + threadIdx.x * 4;
    int add = bsum[blockIdx.x];
    #pragma unroll
    for (int i = 0; i < 4; ++i)
        if (base + i < n) c[base + i] += add;
}

// fill: pos = atomicAdd(&r[d],1); afterwards r[d] == end(d), start(d) == (d ? r[d-1] : 0)
__global__ __launch_bounds__(256) void scatter_kernel(
    const int* __restrict__ src, const int* __restrict__ dst,
    int* __restrict__ r, int* __restrict__ srcs, int E)
{
    int k = blockIdx.x * 256 + threadIdx.x;
    if (k >= E) return;
    int d = dst[k];
    int pos = atomicAdd(&r[d], 1);
    srcs[pos] = src[k];
}

// ---------------- Kernel 3: fused softmax + aggregation, one wave per dst node
__global__ __launch_bounds__(256) void aggregate_kernel(
    const int* __restrict__ r, const int* __restrict__ srcs,
    const float* __restrict__ s_src, const float* __restrict__ s_dst,
    const float* __restrict__ ab, const float* __restrict__ Wh,
    float* __restrict__ out, int N)
{
    int d    = (blockIdx.x * 256 + threadIdx.x) >> 6;
    int lane = threadIdx.x & 63;
    if (d >= N) return;
    int end   = r[d];
    int start = d ? r[d - 1] : 0;
    float sd = s_dst[d] + ab[0];
    float acc = 0.f, dn = 0.f;
    for (int b = start; b < end; b += 64) {
        int cnt = min(64, end - b);
        int sid = 0; float exv = 0.f;
        if (lane < cnt) {
            sid = srcs[b + lane];
            float e = s_src[sid] + sd;
            e = e > 0.f ? e : ALPHA * e;
            exv = __expf(e);
        }
        for (int j = 0; j < cnt; ++j) {
            int   sj = __shfl(sid, j, 64);
            float ej = __shfl(exv, j, 64);
            dn  += ej;
            acc += ej * Wh[(size_t)sj * 64 + lane];
        }
    }
    out[(size_t)d * 64 + lane] = acc / (dn > 0.f ? dn : 1.f);
}

extern "C" void kernel_launch(void* const* d_in, const int* in_sizes, int n_in,
                              void* d_out, int out_size, void* d_ws, size_t ws_size,
                              hipStream_t stream) {
    const float* h   = (const float*)d_in[0];
    const float* W   = (const float*)d_in[1];
    const float* Wb  = (const float*)d_in[2];
    const float* a   = (const float*)d_in[3];
    const float* ab  = (const float*)d_in[4];
    const int*   src = (const int*)d_in[5];
    const int*   dst = (const int*)d_in[6];

    int N = in_sizes[0] / NF;
    int E = in_sizes[5];
    float* out = (float*)d_out;

    // ws layout (30.8 MB, same footprint as round 0):
    float* Wh    = (float*)d_ws;                 // N*64
    float* s_src = Wh + (size_t)N * NF;          // N
    float* s_dst = s_src + N;                    // N
    int*   rptr  = (int*)(s_dst + N);            // N
    int*   srcs  = rptr + N;                     // E
    int*   bsum  = srcs;                         // alias: lifetime ends before scatter writes srcs

    hipMemsetAsync(rptr, 0, (size_t)N * sizeof(int), stream);

    wh_kernel<<<(N + 63) / 64, 256, 0, stream>>>(h, W, Wb, a, Wh, s_src, s_dst, N);
    hist_kernel<<<(E + 255) / 256, 256, 0, stream>>>(dst, rptr, E);

    int nb = (N + 1023) / 1024;                  // 98 <= 256
    scan_a<<<nb, 256, 0, stream>>>(rptr, bsum, N);
    scan_b<<<1, 256, 0, stream>>>(bsum, nb);
    scan_c<<<nb, 256, 0, stream>>>(rptr, bsum, N);

    scatter_kernel<<<(E + 255) / 256, 256, 0, stream>>>(src, dst, rptr, srcs, E);

    long long totalThreads = (long long)N * 64;
    aggregate_kernel<<<(int)((totalThreads + 255) / 256), 256, 0, stream>>>(
        rptr, srcs, s_src, s_dst, ab, Wh, out, N);
}

// Round 3
// 315.870 us; speedup vs baseline: 1.5114x; 1.0032x over previous
//
#include <hip/hip_runtime.h>

#define NF 64
#define ALPHA 0.2f

typedef unsigned int  uint;
typedef unsigned short ushort;

__device__ __forceinline__ ushort f2bf(float x) {
    uint u = __float_as_uint(x);
    u += 0x7fffu + ((u >> 16) & 1u);      // round-to-nearest-even
    return (ushort)(u >> 16);
}

struct us4 { ushort x, y, z, w; };

// ---------------- Fused kernel: [blocks 0..whB) Wh GEMM, [whB..) dst histogram
__global__ __launch_bounds__(256) void wh_hist_kernel(
    const float* __restrict__ h, const float* __restrict__ W,
    const float* __restrict__ Wb, const float* __restrict__ a,
    ushort* __restrict__ whbf, float* __restrict__ s_src, float* __restrict__ s_dst,
    const int* __restrict__ dst, int* __restrict__ rptr,
    int N, int E, int whB)
{
    __shared__ float hs[64 * 68];
    __shared__ float Ws[64 * 64];
    __shared__ float wbs[64], as_[64], ad_[64];
    int t = threadIdx.x;

    if ((int)blockIdx.x >= whB) {
        // ---- histogram: 4 edges per thread via int4
        int base = ((int)blockIdx.x - whB) * 1024 + t * 4;
        if (base + 3 < E) {
            int4 d4 = *(const int4*)&dst[base];
            atomicAdd(&rptr[d4.x], 1); atomicAdd(&rptr[d4.y], 1);
            atomicAdd(&rptr[d4.z], 1); atomicAdd(&rptr[d4.w], 1);
        } else {
            for (int i = base; i < E; ++i) atomicAdd(&rptr[dst[i]], 1);
        }
        return;
    }

    // ---- Wh = h @ W.T + Wb; s_src/s_dst fused dot products
    int r0 = blockIdx.x * 64;
    const float4* W4 = (const float4*)W;
    #pragma unroll
    for (int i = 0; i < 4; ++i) {
        int idx = t + 256 * i;
        int row = idx >> 4, q = idx & 15;
        float4 w = W4[idx];
        *(float4*)&Ws[row * 64 + ((q + row) & 15) * 4] = w;
        float4 v = make_float4(0.f, 0.f, 0.f, 0.f);
        if (r0 + row < N) v = *(const float4*)&h[(size_t)(r0 + row) * 64 + q * 4];
        *(float4*)&hs[row * 68 + q * 4] = v;
    }
    if (t < 64) { wbs[t] = Wb[t]; as_[t] = a[t]; ad_[t] = a[64 + t]; }
    __syncthreads();

    int tr = t >> 4, tc = t & 15;
    float acc[4][4];
    #pragma unroll
    for (int rr = 0; rr < 4; ++rr)
        #pragma unroll
        for (int cc = 0; cc < 4; ++cc) acc[rr][cc] = 0.f;

    #pragma unroll
    for (int k = 0; k < 16; ++k) {
        float4 hv[4], wv[4];
        #pragma unroll
        for (int rr = 0; rr < 4; ++rr)
            hv[rr] = *(float4*)&hs[(4 * tr + rr) * 68 + 4 * k];
        #pragma unroll
        for (int cc = 0; cc < 4; ++cc) {
            int j = 4 * tc + cc;
            wv[cc] = *(float4*)&Ws[j * 64 + ((k + j) & 15) * 4];
        }
        #pragma unroll
        for (int rr = 0; rr < 4; ++rr)
            #pragma unroll
            for (int cc = 0; cc < 4; ++cc)
                acc[rr][cc] += hv[rr].x * wv[cc].x + hv[rr].y * wv[cc].y
                             + hv[rr].z * wv[cc].z + hv[rr].w * wv[cc].w;
    }

    float p1[4], p2[4];
    #pragma unroll
    for (int rr = 0; rr < 4; ++rr) {
        int row = r0 + 4 * tr + rr;
        float4 o;
        o.x = acc[rr][0] + wbs[4 * tc + 0];
        o.y = acc[rr][1] + wbs[4 * tc + 1];
        o.z = acc[rr][2] + wbs[4 * tc + 2];
        o.w = acc[rr][3] + wbs[4 * tc + 3];
        if (row < N) {
            us4 pk; pk.x = f2bf(o.x); pk.y = f2bf(o.y); pk.z = f2bf(o.z); pk.w = f2bf(o.w);
            *(us4*)&whbf[(size_t)row * 64 + 4 * tc] = pk;
        }
        p1[rr] = o.x * as_[4 * tc] + o.y * as_[4 * tc + 1] + o.z * as_[4 * tc + 2] + o.w * as_[4 * tc + 3];
        p2[rr] = o.x * ad_[4 * tc] + o.y * ad_[4 * tc + 1] + o.z * ad_[4 * tc + 2] + o.w * ad_[4 * tc + 3];
    }
    #pragma unroll
    for (int off = 8; off >= 1; off >>= 1) {
        #pragma unroll
        for (int rr = 0; rr < 4; ++rr) {
            p1[rr] += __shfl_down(p1[rr], off, 16);
            p2[rr] += __shfl_down(p2[rr], off, 16);
        }
    }
    if (tc == 0) {
        #pragma unroll
        for (int rr = 0; rr < 4; ++rr) {
            int row = r0 + 4 * tr + rr;
            if (row < N) { s_src[row] = p1[rr]; s_dst[row] = p2[rr]; }
        }
    }
}

// ---------------- exclusive scan (1024/block) ----------------
__global__ __launch_bounds__(256) void scan_a(int* __restrict__ c, int* __restrict__ bsum, int n)
{
    __shared__ int s[256];
    int t = threadIdx.x;
    int base = blockIdx.x * 1024 + t * 4;
    int v0 = 0, v1 = 0, v2 = 0, v3 = 0;
    if (base + 0 < n) v0 = c[base + 0];
    if (base + 1 < n) v1 = c[base + 1];
    if (base + 2 < n) v2 = c[base + 2];
    if (base + 3 < n) v3 = c[base + 3];
    int tsum = v0 + v1 + v2 + v3;
    s[t] = tsum; __syncthreads();
    for (int off = 1; off < 256; off <<= 1) {
        int x = (t >= off) ? s[t - off] : 0;
        __syncthreads();
        s[t] += x;
        __syncthreads();
    }
    int excl = s[t] - tsum;
    if (base + 0 < n) c[base + 0] = excl; excl += v0;
    if (base + 1 < n) c[base + 1] = excl; excl += v1;
    if (base + 2 < n) c[base + 2] = excl; excl += v2;
    if (base + 3 < n) c[base + 3] = excl;
    if (t == 255) bsum[blockIdx.x] = s[255];
}

__global__ __launch_bounds__(256) void scan_b(int* __restrict__ bsum, int nb)
{
    __shared__ int s[256];
    int t = threadIdx.x;
    int v = (t < nb) ? bsum[t] : 0;
    s[t] = v; __syncthreads();
    for (int off = 1; off < 256; off <<= 1) {
        int x = (t >= off) ? s[t - off] : 0;
        __syncthreads();
        s[t] += x;
        __syncthreads();
    }
    if (t < nb) bsum[t] = s[t] - v;
}

__global__ __launch_bounds__(256) void scan_c(int* __restrict__ c, const int* __restrict__ bsum, int n)
{
    int base = blockIdx.x * 1024 + threadIdx.x * 4;
    int add = bsum[blockIdx.x];
    #pragma unroll
    for (int i = 0; i < 4; ++i)
        if (base + i < n) c[base + i] += add;
}

// ---------------- scatter: 2 edges/thread ----------------
__global__ __launch_bounds__(256) void scatter_kernel(
    const int* __restrict__ src, const int* __restrict__ dst,
    int* __restrict__ r, int* __restrict__ srcs, int E)
{
    int k = (blockIdx.x * 256 + threadIdx.x) * 2;
    if (k + 1 < E) {
        int2 s2 = *(const int2*)&src[k];
        int2 d2 = *(const int2*)&dst[k];
        srcs[atomicAdd(&r[d2.x], 1)] = s2.x;
        srcs[atomicAdd(&r[d2.y], 1)] = s2.y;
    } else if (k < E) {
        srcs[atomicAdd(&r[dst[k]], 1)] = src[k];
    }
}

// ---------------- aggregate: 1 wave / dst, 2 edges in flight, bf16 Wh ----------------
__global__ __launch_bounds__(256) void aggregate_kernel(
    const int* __restrict__ r, const int* __restrict__ srcs,
    const float* __restrict__ s_src, const float* __restrict__ s_dst,
    const float* __restrict__ ab, const ushort* __restrict__ whbf,
    float* __restrict__ out, int N)
{
    int d    = (blockIdx.x * 256 + threadIdx.x) >> 6;
    int lane = threadIdx.x & 63;
    if (d >= N) return;
    int half = lane >> 5;          // which edge of the pair
    int fp   = lane & 31;          // feature pair: cols 2*fp, 2*fp+1

    int end   = r[d];
    int start = d ? r[d - 1] : 0;
    float sd = s_dst[d] + ab[0];

    float accx = 0.f, accy = 0.f, dn = 0.f;

    for (int b = start; b < end; b += 64) {
        int cnt = end - b; if (cnt > 64) cnt = 64;
        int sid = 0; float exv = 0.f;
        if (lane < cnt) {
            sid = srcs[b + lane];
            float e = s_src[sid] + sd;
            e = e > 0.f ? e : ALPHA * e;
            exv = __expf(e);
        }
        int trip = (cnt + 1) >> 1;
        // prologue: prefetch pair 0
        int idx = half;
        float ej = __shfl(exv, idx, 64);
        int   sj = __shfl(sid, idx, 64);
        uint  p  = ((const uint*)(whbf + (size_t)sj * 64))[fp];
        for (int j = 0; j < trip; ++j) {
            int idn = 2 * (j + 1) + half;
            int srcl = idn < 64 ? idn : 0;
            float ejn = __shfl(exv, srcl, 64);
            int   sjn = __shfl(sid, srcl, 64);
            uint  pn  = ((const uint*)(whbf + (size_t)sjn * 64))[fp]; // prefetch next
            float v0 = __uint_as_float(p << 16);
            float v1 = __uint_as_float(p & 0xffff0000u);
            accx += ej * v0; accy += ej * v1; dn += ej;
            ej = (idn < cnt) ? ejn : 0.f;
            p = pn;
        }
    }
    // combine the two half-wave partials
    accx += __shfl(accx, lane ^ 32, 64);
    accy += __shfl(accy, lane ^ 32, 64);
    dn   += __shfl(dn,   lane ^ 32, 64);
    if (half == 0) {
        float inv = 1.f / (dn > 0.f ? dn : 1.f);
        float2 o; o.x = accx * inv; o.y = accy * inv;
        *(float2*)&out[(size_t)d * 64 + 2 * fp] = o;
    }
}

extern "C" void kernel_launch(void* const* d_in, const int* in_sizes, int n_in,
                              void* d_out, int out_size, void* d_ws, size_t ws_size,
                              hipStream_t stream) {
    const float* h   = (const float*)d_in[0];
    const float* W   = (const float*)d_in[1];
    const float* Wb  = (const float*)d_in[2];
    const float* a   = (const float*)d_in[3];
    const float* ab  = (const float*)d_in[4];
    const int*   src = (const int*)d_in[5];
    const int*   dst = (const int*)d_in[6];

    int N = in_sizes[0] / NF;
    int E = in_sizes[5];
    float* out = (float*)d_out;

    // ws layout (well under round-0 footprint):
    ushort* whbf  = (ushort*)d_ws;                     // N*64 bf16 (12.8 MB)
    float*  s_src = (float*)(whbf + (size_t)N * NF);   // N
    float*  s_dst = s_src + N;                         // N
    int*    rptr  = (int*)(s_dst + N);                 // N
    int*    srcs  = rptr + N;                          // E
    int*    bsum  = srcs;                              // alias; dead before scatter

    hipMemsetAsync(rptr, 0, (size_t)N * sizeof(int), stream);

    int whB   = (N + 63) / 64;
    int histB = (E + 1023) / 1024;
    wh_hist_kernel<<<whB + histB, 256, 0, stream>>>(
        h, W, Wb, a, whbf, s_src, s_dst, dst, rptr, N, E, whB);

    int nb = (N + 1023) / 1024;
    scan_a<<<nb, 256, 0, stream>>>(rptr, bsum, N);
    scan_b<<<1, 256, 0, stream>>>(bsum, nb);
    scan_c<<<nb, 256, 0, stream>>>(rptr, bsum, N);

    scatter_kernel<<<(E / 2 + 255) / 256 + 1, 256, 0, stream>>>(src, dst, rptr, srcs, E);

    long long totalThreads = (long long)N * 64;
    aggregate_kernel<<<(int)((totalThreads + 255) / 256), 256, 0, stream>>>(
        rptr, srcs, s_src, s_dst, ab, whbf, out, N);
}

// Round 4
// 264.030 us; speedup vs baseline: 1.8081x; 1.1963x over previous
//
#include <hip/hip_runtime.h>

#define NF 64
#define ALPHA 0.2f

typedef unsigned int  uint;
typedef unsigned short ushort;

typedef __attribute__((ext_vector_type(8))) short  short8;   // 8 bf16 (4 VGPRs)
typedef __attribute__((ext_vector_type(4))) float  floatx4;  // MFMA acc

__device__ __forceinline__ ushort f2bf(float x) {
    uint u = __float_as_uint(x);
    u += 0x7fffu + ((u >> 16) & 1u);      // round-to-nearest-even
    return (ushort)(u >> 16);
}

__device__ __forceinline__ short8 pack8(float4 lo, float4 hi) {
    short8 r;
    r[0] = (short)f2bf(lo.x); r[1] = (short)f2bf(lo.y);
    r[2] = (short)f2bf(lo.z); r[3] = (short)f2bf(lo.w);
    r[4] = (short)f2bf(hi.x); r[5] = (short)f2bf(hi.y);
    r[6] = (short)f2bf(hi.z); r[7] = (short)f2bf(hi.w);
    return r;
}

// ---------------- Fused: [0..whB) MFMA Wh GEMM (16 rows/wave), [whB..) dst histogram
// No LDS, ~80 VGPR -> high occupancy for both halves.
__global__ __launch_bounds__(256) void wh_hist_kernel(
    const float* __restrict__ h, const float* __restrict__ W,
    const float* __restrict__ Wb, const float* __restrict__ a,
    ushort* __restrict__ whbf, float* __restrict__ s_src, float* __restrict__ s_dst,
    const int* __restrict__ dst, int* __restrict__ rptr,
    int N, int E, int whB)
{
    int t = threadIdx.x;
    if ((int)blockIdx.x >= whB) {
        int base = ((int)blockIdx.x - whB) * 1024 + t * 4;
        if (base + 3 < E) {
            int4 d4 = *(const int4*)&dst[base];
            atomicAdd(&rptr[d4.x], 1); atomicAdd(&rptr[d4.y], 1);
            atomicAdd(&rptr[d4.z], 1); atomicAdd(&rptr[d4.w], 1);
        } else {
            for (int i = base; i < E; ++i) atomicAdd(&rptr[dst[i]], 1);
        }
        return;
    }

    int lane = t & 63;
    int wave = t >> 6;
    int r0   = blockIdx.x * 64 + wave * 16;     // 16 rows per wave
    if (r0 >= N) return;                        // N%16==0 -> whole wave in/out
    int m    = lane & 15;                       // A row / B col within tile
    int quad = lane >> 4;                       // k-group: k = quad*8 + j

    // B fragments: b[ct][kh] lane elem j = W[ct*16+m][kh*32+quad*8+j]  (contig 32B)
    short8 bfrag[4][2];
    #pragma unroll
    for (int ct = 0; ct < 4; ++ct) {
        const float* wrow = W + (size_t)(ct * 16 + m) * 64 + quad * 8;
        #pragma unroll
        for (int kh = 0; kh < 2; ++kh) {
            float4 lo = *(const float4*)(wrow + kh * 32);
            float4 hi = *(const float4*)(wrow + kh * 32 + 4);
            bfrag[ct][kh] = pack8(lo, hi);
        }
    }

    // A fragments from h, 2 k-halves; D[m][n] accumulated fp32
    int row_a = r0 + m; if (row_a >= N) row_a = N - 1;
    const float* hrow = h + (size_t)row_a * 64 + quad * 8;
    floatx4 zero = {0.f, 0.f, 0.f, 0.f};
    floatx4 acc[4] = {zero, zero, zero, zero};
    #pragma unroll
    for (int kh = 0; kh < 2; ++kh) {
        float4 lo = *(const float4*)(hrow + kh * 32);
        float4 hi = *(const float4*)(hrow + kh * 32 + 4);
        short8 af = pack8(lo, hi);
        #pragma unroll
        for (int ct = 0; ct < 4; ++ct)
            acc[ct] = __builtin_amdgcn_mfma_f32_16x16x32_bf16(af, bfrag[ct][kh], acc[ct], 0, 0, 0);
    }

    // Epilogue: bias, bf16 store (C/D map: col=ct*16+m, row=r0+quad*4+reg),
    // fused s_src/s_dst dot products from fp32 accumulators.
    float p1[4] = {0.f, 0.f, 0.f, 0.f}, p2[4] = {0.f, 0.f, 0.f, 0.f};
    #pragma unroll
    for (int ct = 0; ct < 4; ++ct) {
        int col = ct * 16 + m;
        float wb  = Wb[col];
        float av1 = a[col];
        float av2 = a[64 + col];
        #pragma unroll
        for (int reg = 0; reg < 4; ++reg) {
            int row = r0 + quad * 4 + reg;
            float v = acc[ct][reg] + wb;
            if (row < N) whbf[(size_t)row * 64 + col] = f2bf(v);
            p1[reg] += v * av1;
            p2[reg] += v * av2;
        }
    }
    #pragma unroll
    for (int off = 8; off >= 1; off >>= 1) {
        #pragma unroll
        for (int reg = 0; reg < 4; ++reg) {
            p1[reg] += __shfl_down(p1[reg], off, 16);
            p2[reg] += __shfl_down(p2[reg], off, 16);
        }
    }
    if (m == 0) {
        #pragma unroll
        for (int reg = 0; reg < 4; ++reg) {
            int row = r0 + quad * 4 + reg;
            if (row < N) { s_src[row] = p1[reg]; s_dst[row] = p2[reg]; }
        }
    }
}

// ---------------- exclusive scan (1024/block) ----------------
__global__ __launch_bounds__(256) void scan_a(int* __restrict__ c, int* __restrict__ bsum, int n)
{
    __shared__ int s[256];
    int t = threadIdx.x;
    int base = blockIdx.x * 1024 + t * 4;
    int v0 = 0, v1 = 0, v2 = 0, v3 = 0;
    if (base + 0 < n) v0 = c[base + 0];
    if (base + 1 < n) v1 = c[base + 1];
    if (base + 2 < n) v2 = c[base + 2];
    if (base + 3 < n) v3 = c[base + 3];
    int tsum = v0 + v1 + v2 + v3;
    s[t] = tsum; __syncthreads();
    for (int off = 1; off < 256; off <<= 1) {
        int x = (t >= off) ? s[t - off] : 0;
        __syncthreads();
        s[t] += x;
        __syncthreads();
    }
    int excl = s[t] - tsum;
    if (base + 0 < n) c[base + 0] = excl; excl += v0;
    if (base + 1 < n) c[base + 1] = excl; excl += v1;
    if (base + 2 < n) c[base + 2] = excl; excl += v2;
    if (base + 3 < n) c[base + 3] = excl;
    if (t == 255) bsum[blockIdx.x] = s[255];
}

__global__ __launch_bounds__(256) void scan_b(int* __restrict__ bsum, int nb)
{
    __shared__ int s[256];
    int t = threadIdx.x;
    int v = (t < nb) ? bsum[t] : 0;
    s[t] = v; __syncthreads();
    for (int off = 1; off < 256; off <<= 1) {
        int x = (t >= off) ? s[t - off] : 0;
        __syncthreads();
        s[t] += x;
        __syncthreads();
    }
    if (t < nb) bsum[t] = s[t] - v;
}

__global__ __launch_bounds__(256) void scan_c(int* __restrict__ c, const int* __restrict__ bsum, int n)
{
    int base = blockIdx.x * 1024 + threadIdx.x * 4;
    int add = bsum[blockIdx.x];
    #pragma unroll
    for (int i = 0; i < 4; ++i)
        if (base + i < n) c[base + i] += add;
}

// ---------------- scatter: 2 edges/thread ----------------
__global__ __launch_bounds__(256) void scatter_kernel(
    const int* __restrict__ src, const int* __restrict__ dst,
    int* __restrict__ r, int* __restrict__ srcs, int E)
{
    int k = (blockIdx.x * 256 + threadIdx.x) * 2;
    if (k + 1 < E) {
        int2 s2 = *(const int2*)&src[k];
        int2 d2 = *(const int2*)&dst[k];
        srcs[atomicAdd(&r[d2.x], 1)] = s2.x;
        srcs[atomicAdd(&r[d2.y], 1)] = s2.y;
    } else if (k < E) {
        srcs[atomicAdd(&r[dst[k]], 1)] = src[k];
    }
}

// ---------------- aggregate: 1 wave / dst, 2 edges in flight, bf16 Wh ----------------
__global__ __launch_bounds__(256) void aggregate_kernel(
    const int* __restrict__ r, const int* __restrict__ srcs,
    const float* __restrict__ s_src, const float* __restrict__ s_dst,
    const float* __restrict__ ab, const ushort* __restrict__ whbf,
    float* __restrict__ out, int N)
{
    int d    = (blockIdx.x * 256 + threadIdx.x) >> 6;
    int lane = threadIdx.x & 63;
    if (d >= N) return;
    int half = lane >> 5;          // which edge of the pair
    int fp   = lane & 31;          // feature pair: cols 2*fp, 2*fp+1

    int end   = r[d];
    int start = d ? r[d - 1] : 0;
    float sd = s_dst[d] + ab[0];

    float accx = 0.f, accy = 0.f, dn = 0.f;

    for (int b = start; b < end; b += 64) {
        int cnt = end - b; if (cnt > 64) cnt = 64;
        int sid = 0; float exv = 0.f;
        if (lane < cnt) {
            sid = srcs[b + lane];
            float e = s_src[sid] + sd;
            e = e > 0.f ? e : ALPHA * e;
            exv = __expf(e);
        }
        int trip = (cnt + 1) >> 1;
        int idx = half;
        float ej = __shfl(exv, idx, 64);
        int   sj = __shfl(sid, idx, 64);
        uint  p  = ((const uint*)(whbf + (size_t)sj * 64))[fp];
        for (int j = 0; j < trip; ++j) {
            int idn = 2 * (j + 1) + half;
            int srcl = idn < 64 ? idn : 0;
            float ejn = __shfl(exv, srcl, 64);
            int   sjn = __shfl(sid, srcl, 64);
            uint  pn  = ((const uint*)(whbf + (size_t)sjn * 64))[fp]; // prefetch next
            float v0 = __uint_as_float(p << 16);
            float v1 = __uint_as_float(p & 0xffff0000u);
            accx += ej * v0; accy += ej * v1; dn += ej;
            ej = (idn < cnt) ? ejn : 0.f;
            p = pn;
        }
    }
    accx += __shfl(accx, lane ^ 32, 64);
    accy += __shfl(accy, lane ^ 32, 64);
    dn   += __shfl(dn,   lane ^ 32, 64);
    if (half == 0) {
        float inv = 1.f / (dn > 0.f ? dn : 1.f);
        float2 o; o.x = accx * inv; o.y = accy * inv;
        *(float2*)&out[(size_t)d * 64 + 2 * fp] = o;
    }
}

extern "C" void kernel_launch(void* const* d_in, const int* in_sizes, int n_in,
                              void* d_out, int out_size, void* d_ws, size_t ws_size,
                              hipStream_t stream) {
    const float* h   = (const float*)d_in[0];
    const float* W   = (const float*)d_in[1];
    const float* Wb  = (const float*)d_in[2];
    const float* a   = (const float*)d_in[3];
    const float* ab  = (const float*)d_in[4];
    const int*   src = (const int*)d_in[5];
    const int*   dst = (const int*)d_in[6];

    int N = in_sizes[0] / NF;
    int E = in_sizes[5];
    float* out = (float*)d_out;

    ushort* whbf  = (ushort*)d_ws;                     // N*64 bf16 (12.8 MB)
    float*  s_src = (float*)(whbf + (size_t)N * NF);   // N
    float*  s_dst = s_src + N;                         // N
    int*    rptr  = (int*)(s_dst + N);                 // N
    int*    srcs  = rptr + N;                          // E
    int*    bsum  = srcs;                              // alias; dead before scatter

    hipMemsetAsync(rptr, 0, (size_t)N * sizeof(int), stream);

    int whB   = (N + 63) / 64;
    int histB = (E + 1023) / 1024;
    wh_hist_kernel<<<whB + histB, 256, 0, stream>>>(
        h, W, Wb, a, whbf, s_src, s_dst, dst, rptr, N, E, whB);

    int nb = (N + 1023) / 1024;
    scan_a<<<nb, 256, 0, stream>>>(rptr, bsum, N);
    scan_b<<<1, 256, 0, stream>>>(bsum, nb);
    scan_c<<<nb, 256, 0, stream>>>(rptr, bsum, N);

    scatter_kernel<<<(E / 2 + 255) / 256 + 1, 256, 0, stream>>>(src, dst, rptr, srcs, E);

    long long totalThreads = (long long)N * 64;
    aggregate_kernel<<<(int)((totalThreads + 255) / 256), 256, 0, stream>>>(
        rptr, srcs, s_src, s_dst, ab, whbf, out, N);
}